// Round 6
// baseline (507.857 us; speedup 1.0000x reference)
//
#include <hip/hip_runtime.h>

// GAT 3-layer (N=50000, E=800000 (+N self loops), H=2, C=64, widths 128)
// Round 6: two-phase fused_agg — phase 1 vectorizes logits/exp across lanes
// (1 exp per 32 edges instead of ~1.5/edge), phase 2 is gather+fma only.
// bn_stats folded into fused_agg via grid-stride + register accumulation.

#define N_NODES 50000
#define N_EDGES 800000
#define ET (N_EDGES + N_NODES)   // 850000 incl self loops
#define FDIM 128
#define SLOPE 0.2f
#define BN_EPS 1e-5f
#define SCAN_NB 196              // ceil(50000/256)
#define AGG_NB 1568              // fused_agg blocks; 6272 waves, ~8 nodes/wave
#define AGG_STRIDE (AGG_NB * 4)

typedef __attribute__((ext_vector_type(8))) short bf16x8;
typedef __attribute__((ext_vector_type(4))) float f32x4;
typedef __attribute__((ext_vector_type(8))) unsigned short u16x8;

__device__ __forceinline__ unsigned short f2bf(float f) {
  unsigned u = __float_as_uint(f);
  u = u + 0x7fffu + ((u >> 16) & 1u);   // RNE
  return (unsigned short)(u >> 16);
}
__device__ __forceinline__ float bflo(unsigned p) { return __uint_as_float(p << 16); }
__device__ __forceinline__ float bfhi(unsigned p) { return __uint_as_float(p & 0xffff0000u); }

// ---------------- CSR build ----------------

__global__ __launch_bounds__(256) void hist_kernel(const int* __restrict__ dst,
                                                   int* __restrict__ counts) {
  int i = blockIdx.x * 256 + threadIdx.x;
  if (i >= ET) return;
  int d = (i < N_EDGES) ? dst[i] : i - N_EDGES;
  atomicAdd(&counts[d], 1);
}

__global__ __launch_bounds__(256) void scan_blk(const int* __restrict__ counts,
                                                int* __restrict__ rowptr,
                                                int* __restrict__ partials) {
  int i = blockIdx.x * 256 + threadIdx.x;
  int lane = threadIdx.x & 63, wv = threadIdx.x >> 6;
  int c = (i < N_NODES) ? counts[i] : 0;
  int v = c;
#pragma unroll
  for (int off = 1; off < 64; off <<= 1) {
    int u = __shfl_up(v, off);
    if (lane >= off) v += u;
  }
  __shared__ int wsum[4];
  if (lane == 63) wsum[wv] = v;
  __syncthreads();
  int add = 0;
  for (int w = 0; w < wv; ++w) add += wsum[w];
  if (i < N_NODES) rowptr[i] = v - c + add;
  if (threadIdx.x == 255) partials[blockIdx.x] = add + v;
}

__global__ __launch_bounds__(256) void scan_top(int* __restrict__ partials) {
  int t = threadIdx.x;
  int lane = t & 63, wv = t >> 6;
  int c = (t < SCAN_NB) ? partials[t] : 0;
  int v = c;
#pragma unroll
  for (int off = 1; off < 64; off <<= 1) {
    int u = __shfl_up(v, off);
    if (lane >= off) v += u;
  }
  __shared__ int wsum[4];
  if (lane == 63) wsum[wv] = v;
  __syncthreads();
  int add = 0;
  for (int w = 0; w < wv; ++w) add += wsum[w];
  if (t < SCAN_NB) partials[t] = v - c + add;
}

__global__ __launch_bounds__(256) void scan_fin(int* __restrict__ rowptr,
                                                const int* __restrict__ partials,
                                                int* __restrict__ fill) {
  int i = blockIdx.x * 256 + threadIdx.x;
  if (i >= N_NODES) return;
  int v = rowptr[i] + partials[blockIdx.x];
  rowptr[i] = v;
  fill[i] = v;
  if (i == 0) rowptr[N_NODES] = ET;
}

__global__ __launch_bounds__(256) void scatter_kernel(const int* __restrict__ src,
                                                      const int* __restrict__ dst,
                                                      int* __restrict__ fill,
                                                      int* __restrict__ csr_src) {
  int i = blockIdx.x * 256 + threadIdx.x;
  if (i >= ET) return;
  int s, d;
  if (i < N_EDGES) { s = src[i]; d = dst[i]; } else { s = d = i - N_EDGES; }
  int pos = atomicAdd(&fill[d], 1);
  csr_src[pos] = s;
}

// ---------------- W repack: all 3 layers -> B-fragment order, bf16 ----------------
__global__ __launch_bounds__(256) void repack_w(const float* __restrict__ W0,
                                                const float* __restrict__ W1,
                                                const float* __restrict__ W2,
                                                unsigned short* __restrict__ Wr) {
  int i = blockIdx.x * 256 + threadIdx.x;
  if (i >= 3 * 16384) return;
  int L = i >> 14, rem = i & 16383;
  int t  = rem >> 11;
  int ks = (rem >> 9) & 3;
  int ln = (rem >> 3) & 63;
  int j  = rem & 7;
  int k   = ks * 32 + (ln >> 4) * 8 + j;
  int col = t * 16 + (ln & 15);
  const float* W = (L == 0) ? W0 : ((L == 1) ? W1 : W2);
  Wr[i] = f2bf(W[k * 128 + col]);
}

// ---------------- MFMA gemm + BN/ReLU prologue + att-logit epilogue ----------------
__global__ __launch_bounds__(256) void gemm_mfma(const float* __restrict__ Xin,
                                                 const unsigned short* __restrict__ WrL,
                                                 const float* __restrict__ bna,
                                                 const float* __restrict__ g,
                                                 const float* __restrict__ be,
                                                 const float* __restrict__ a_src,
                                                 const float* __restrict__ a_dst,
                                                 unsigned short* __restrict__ Hbf,
                                                 float* __restrict__ als,
                                                 float* __restrict__ ald,
                                                 int doBN) {
  __shared__ unsigned short lds[4][16][128];
  int lane = threadIdx.x & 63;
  int wv   = threadIdx.x >> 6;
  int row0 = blockIdx.x * 64 + wv * 16;
  int gidx = lane & 15;
  int quad = lane >> 4;
  int rA   = row0 + gidx;
  int rAc  = rA < N_NODES ? rA : N_NODES - 1;
  int koff = quad * 8;

  f32x4 acc[8] = {};
#pragma unroll
  for (int ks = 0; ks < 4; ++ks) {
    int cb = ks * 32 + koff;
    const float4* xr = (const float4*)(Xin + (size_t)rAc * FDIM + cb);
    float4 xa = xr[0], xb = xr[1];
    float xv[8] = {xa.x, xa.y, xa.z, xa.w, xb.x, xb.y, xb.z, xb.w};
    bf16x8 afrag;
    if (doBN) {
#pragma unroll
      for (int j = 0; j < 8; ++j) {
        int c = cb + j;
        float mu  = bna[c] * (1.f / N_NODES);
        float var = bna[128 + c] * (1.f / N_NODES) - mu * mu;
        float v = (xv[j] - mu) * rsqrtf(var + BN_EPS) * g[c] + be[c];
        v = v > 0.f ? v : 0.f;
        afrag[j] = (short)f2bf(v);
      }
    } else {
#pragma unroll
      for (int j = 0; j < 8; ++j) afrag[j] = (short)f2bf(xv[j]);
    }
#pragma unroll
    for (int t = 0; t < 8; ++t) {
      bf16x8 bfrag = *(const bf16x8*)(WrL + ((size_t)((t * 4 + ks) * 64 + lane)) * 8);
      acc[t] = __builtin_amdgcn_mfma_f32_16x16x32_bf16(afrag, bfrag, acc[t], 0, 0, 0);
    }
  }

  // ---- attention-logit epilogue: lane holds D[row=(quad*4+r)][col=t*16+gidx]
  float vs[2][4] = {}, vd[2][4] = {};
#pragma unroll
  for (int t = 0; t < 8; ++t) {
    int col = t * 16 + gidx;
    float as = a_src[col], ad = a_dst[col];
    int hd = t >> 2;
#pragma unroll
    for (int r = 0; r < 4; ++r) {
      vs[hd][r] = fmaf(acc[t][r], as, vs[hd][r]);
      vd[hd][r] = fmaf(acc[t][r], ad, vd[hd][r]);
    }
  }
#pragma unroll
  for (int off = 1; off < 16; off <<= 1) {
#pragma unroll
    for (int hd = 0; hd < 2; ++hd)
#pragma unroll
      for (int r = 0; r < 4; ++r) {
        vs[hd][r] += __shfl_xor(vs[hd][r], off);
        vd[hd][r] += __shfl_xor(vd[hd][r], off);
      }
  }
  if (gidx == 0) {
#pragma unroll
    for (int r = 0; r < 4; ++r) {
      int row = row0 + quad * 4 + r;
      if (row < N_NODES) {
        als[row * 2 + 0] = vs[0][r]; als[row * 2 + 1] = vs[1][r];
        ald[row * 2 + 0] = vd[0][r]; ald[row * 2 + 1] = vd[1][r];
      }
    }
  }

  // ---- bf16 H store via LDS transpose ----
#pragma unroll
  for (int t = 0; t < 8; ++t)
#pragma unroll
    for (int r = 0; r < 4; ++r)
      lds[wv][quad * 4 + r][t * 16 + gidx] = f2bf(acc[t][r]);
  __syncthreads();
#pragma unroll
  for (int it = 0; it < 4; ++it) {
    int rloc = it * 4 + quad;
    int row = row0 + rloc;
    if (row < N_NODES)
      *(u16x8*)(Hbf + (size_t)row * FDIM + gidx * 8) = *(u16x8*)&lds[wv][rloc][gidx * 8];
  }
}

// ---------------- two-phase fused softmax-aggregate (+BN stats) ----------------
// Grid-stride: wave w handles nodes w, w+6272, ... Lane owns channels
// (2*lane, 2*lane+1); lanes 0-31 = head 0, 32-63 = head 1 for softmax state.
// Phase 1 per <=32-edge chunk: lane li loads edge chunk+li's logit, half-wave
// max -> one exp -> half-wave sum. Phase 2: gather H rows, 2 fma/edge.
// mode 0: write A fp32 [N,128] + accumulate BN sums into bna[256].
// mode 2: head-mean + b2 -> out fp32 [N,64].
__global__ __launch_bounds__(256) void fused_agg(const int* __restrict__ rowptr,
                                                 const int* __restrict__ csr_src,
                                                 const unsigned* __restrict__ H2,
                                                 const float* __restrict__ als,
                                                 const float* __restrict__ ald,
                                                 float* __restrict__ A,
                                                 float* __restrict__ out,
                                                 const float* __restrict__ b2,
                                                 float* __restrict__ bna,
                                                 int mode) {
  int lane = threadIdx.x & 63;
  int li   = lane & 31;
  int ebase = lane & 32;               // shfl base for this lane's head
  int wid = blockIdx.x * 4 + (threadIdx.x >> 6);
  float bs0 = 0.f, bs1 = 0.f, bq0 = 0.f, bq1 = 0.f;

  for (int n = wid; n < N_NODES; n += AGG_STRIDE) {
    int beg = rowptr[n], end = rowptr[n + 1];
    float2 adv = ((const float2*)ald)[n];
    float advh = (lane >= 32) ? adv.y : adv.x;
    float m_run = -__builtin_inff(), l_run = 0.f, ox = 0.f, oy = 0.f;

    for (int chunk = beg; chunk < end; chunk += 32) {
      int cnt = end - chunk; cnt = cnt > 32 ? 32 : cnt;
      // ---- phase 1: vectorized logits over lanes ----
      int eidx = chunk + (li < cnt ? li : cnt - 1);
      int s = csr_src[eidx];
      float2 al = ((const float2*)als)[s];
      float v = ((lane >= 32) ? al.y : al.x) + advh;
      v = v > 0.f ? v : SLOPE * v;
      if (li >= cnt) v = -__builtin_inff();
      float mv = v;
#pragma unroll
      for (int off = 1; off < 32; off <<= 1) mv = fmaxf(mv, __shfl_xor(mv, off));
      float m_new = fmaxf(m_run, mv);
      float sc = __expf(m_run - m_new);   // first chunk: exp(-inf)=0
      float e = __expf(v - m_new);        // padded lanes -> 0
      float ls = e;
#pragma unroll
      for (int off = 1; off < 32; off <<= 1) ls += __shfl_xor(ls, off);
      l_run = fmaf(l_run, sc, ls);
      ox *= sc; oy *= sc;
      m_run = m_new;
      // ---- phase 2: gather + weighted accumulate ----
      int j = 0;
      for (; j + 4 <= cnt; j += 4) {
        int s0 = __shfl(s, j),     s1 = __shfl(s, j + 1);
        int s2 = __shfl(s, j + 2), s3 = __shfl(s, j + 3);
        unsigned h0 = H2[s0 * 64 + lane];
        unsigned h1 = H2[s1 * 64 + lane];
        unsigned h2 = H2[s2 * 64 + lane];
        unsigned h3 = H2[s3 * 64 + lane];
        float e0 = __shfl(e, ebase + j),     e1 = __shfl(e, ebase + j + 1);
        float e2 = __shfl(e, ebase + j + 2), e3 = __shfl(e, ebase + j + 3);
        ox = fmaf(e0, bflo(h0), ox); oy = fmaf(e0, bfhi(h0), oy);
        ox = fmaf(e1, bflo(h1), ox); oy = fmaf(e1, bfhi(h1), oy);
        ox = fmaf(e2, bflo(h2), ox); oy = fmaf(e2, bfhi(h2), oy);
        ox = fmaf(e3, bflo(h3), ox); oy = fmaf(e3, bfhi(h3), oy);
      }
      for (; j < cnt; ++j) {
        int sj = __shfl(s, j);
        unsigned hj = H2[sj * 64 + lane];
        float ej = __shfl(e, ebase + j);
        ox = fmaf(ej, bflo(hj), ox); oy = fmaf(ej, bfhi(hj), oy);
      }
    }
    float inv = 1.f / (l_run + 1e-16f);
    ox *= inv; oy *= inv;
    if (mode == 0) {
      float2 outv = {ox, oy};
      *(float2*)(A + (size_t)n * FDIM + lane * 2) = outv;
      bs0 += ox; bs1 += oy;
      bq0 = fmaf(ox, ox, bq0); bq1 = fmaf(oy, oy, bq1);
    } else {
      float px = __shfl_xor(ox, 32);
      float py = __shfl_xor(oy, 32);
      if (lane < 32) {
        int c = lane * 2;
        float2 outv = {0.5f * (ox + px) + b2[c], 0.5f * (oy + py) + b2[c + 1]};
        *(float2*)(out + (size_t)n * 64 + c) = outv;
      }
    }
  }

  if (mode == 0) {
    // reduce BN partials across the block's 4 waves, then atomics (conflict-free LDS)
    __shared__ float sh[4][4][64];
    int wv = threadIdx.x >> 6;
    sh[wv][0][lane] = bs0; sh[wv][1][lane] = bs1;
    sh[wv][2][lane] = bq0; sh[wv][3][lane] = bq1;
    __syncthreads();
    if (threadIdx.x < 64) {
      int t = threadIdx.x;
      float a0 = 0.f, a1 = 0.f, a2 = 0.f, a3 = 0.f;
#pragma unroll
      for (int w = 0; w < 4; ++w) {
        a0 += sh[w][0][t]; a1 += sh[w][1][t];
        a2 += sh[w][2][t]; a3 += sh[w][3][t];
      }
      atomicAdd(&bna[2 * t],           a0);
      atomicAdd(&bna[2 * t + 1],       a1);
      atomicAdd(&bna[128 + 2 * t],     a2);
      atomicAdd(&bna[128 + 2 * t + 1], a3);
    }
  }
}

extern "C" void kernel_launch(void* const* d_in, const int* in_sizes, int n_in,
                              void* d_out, int out_size, void* d_ws, size_t ws_size,
                              hipStream_t stream) {
  const float* x  = (const float*)d_in[0];
  const int*   ei = (const int*)d_in[1];
  const int* src = ei;
  const int* dst = ei + N_EDGES;

  const float* W[3]    = {(const float*)d_in[2],  (const float*)d_in[8],  (const float*)d_in[14]};
  const float* asrc[3] = {(const float*)d_in[3],  (const float*)d_in[9],  (const float*)d_in[15]};
  const float* adst[3] = {(const float*)d_in[4],  (const float*)d_in[10], (const float*)d_in[16]};
  const float* g[2]    = {(const float*)d_in[6],  (const float*)d_in[12]};
  const float* be[2]   = {(const float*)d_in[7],  (const float*)d_in[13]};
  const float* b2      = (const float*)d_in[17];

  // workspace (4-byte units, every region 16B-aligned):
  int*   counts   = (int*)d_ws;
  int*   rowptr   = counts + 50048;
  int*   fill     = rowptr + 50048;
  int*   partials = fill + 50048;
  int*   csr_src  = partials + 256;
  float* bna      = (float*)(csr_src + 850048);
  float* als      = bna + 256;
  float* ald      = als + 100096;
  unsigned short* Wr  = (unsigned short*)(ald + 100096);
  unsigned short* Hbf = Wr + 3 * 16384;
  float* A        = (float*)(Hbf + (size_t)N_NODES * FDIM);

  // ---- build CSR + repack W (edge set / weights constant across layers) ----
  hipMemsetAsync(counts, 0, (size_t)N_NODES * sizeof(int), stream);
  hist_kernel<<<(ET + 255) / 256, 256, 0, stream>>>(dst, counts);
  scan_blk<<<SCAN_NB, 256, 0, stream>>>(counts, rowptr, partials);
  scan_top<<<1, 256, 0, stream>>>(partials);
  scan_fin<<<SCAN_NB, 256, 0, stream>>>(rowptr, partials, fill);
  scatter_kernel<<<(ET + 255) / 256, 256, 0, stream>>>(src, dst, fill, csr_src);
  repack_w<<<(3 * 16384 + 255) / 256, 256, 0, stream>>>(W[0], W[1], W[2], Wr);

  const int gemm_grid = (N_NODES + 63) / 64;

  for (int L = 0; L < 3; ++L) {
    const float* fin = (L == 0) ? x : A;
    int doBN = (L > 0);
    const float* gg = doBN ? g[L - 1]  : (const float*)nullptr;
    const float* bb = doBN ? be[L - 1] : (const float*)nullptr;
    gemm_mfma<<<gemm_grid, 256, 0, stream>>>(fin, Wr + (size_t)L * 16384, bna, gg, bb,
                                             asrc[L], adst[L], Hbf, als, ald, doBN);
    if (L < 2)
      hipMemsetAsync(bna, 0, 256 * sizeof(float), stream);  // after gemm consumed it
    fused_agg<<<AGG_NB, 256, 0, stream>>>(rowptr, csr_src, (const unsigned*)Hbf,
                                          als, ald, A, (float*)d_out, b2, bna,
                                          (L == 2) ? 2 : 0);
  }
}

// Round 7
// 372.336 us; speedup vs baseline: 1.3640x; 1.3640x over previous
//
#include <hip/hip_runtime.h>

// GAT 3-layer (N=50000, E=800000 (+N self loops), H=2, C=64, widths 128)
// Round 7: revert to one-wave-per-node fused_agg (R6 two-phase regressed:
// TLP 8x down + serial shfl/gather chain). New: no-max-shift softmax (logits
// bounded ~|10|, exp safe; removes the loop-carried max->exp->rescale chain),
// 4-edge unroll with clamped 4-deep prefetch, scalar csr/als loads via
// readfirstlane, BN stats fused (block reduce -> 32-slot atomics + tiny
// reduce_bna kernel) eliminating both bn_stats passes.

#define N_NODES 50000
#define N_EDGES 800000
#define ET (N_EDGES + N_NODES)   // 850000 incl self loops
#define FDIM 128
#define SLOPE 0.2f
#define BN_EPS 1e-5f
#define SCAN_NB 196              // ceil(50000/256)

typedef __attribute__((ext_vector_type(8))) short bf16x8;
typedef __attribute__((ext_vector_type(4))) float f32x4;
typedef __attribute__((ext_vector_type(8))) unsigned short u16x8;

__device__ __forceinline__ unsigned short f2bf(float f) {
  unsigned u = __float_as_uint(f);
  u = u + 0x7fffu + ((u >> 16) & 1u);   // RNE
  return (unsigned short)(u >> 16);
}
__device__ __forceinline__ float bflo(unsigned p) { return __uint_as_float(p << 16); }
__device__ __forceinline__ float bfhi(unsigned p) { return __uint_as_float(p & 0xffff0000u); }

// ---------------- CSR build ----------------

__global__ __launch_bounds__(256) void hist_kernel(const int* __restrict__ dst,
                                                   int* __restrict__ counts) {
  int i = blockIdx.x * 256 + threadIdx.x;
  if (i >= ET) return;
  int d = (i < N_EDGES) ? dst[i] : i - N_EDGES;
  atomicAdd(&counts[d], 1);
}

__global__ __launch_bounds__(256) void scan_blk(const int* __restrict__ counts,
                                                int* __restrict__ rowptr,
                                                int* __restrict__ partials) {
  int i = blockIdx.x * 256 + threadIdx.x;
  int lane = threadIdx.x & 63, wv = threadIdx.x >> 6;
  int c = (i < N_NODES) ? counts[i] : 0;
  int v = c;
#pragma unroll
  for (int off = 1; off < 64; off <<= 1) {
    int u = __shfl_up(v, off);
    if (lane >= off) v += u;
  }
  __shared__ int wsum[4];
  if (lane == 63) wsum[wv] = v;
  __syncthreads();
  int add = 0;
  for (int w = 0; w < wv; ++w) add += wsum[w];
  if (i < N_NODES) rowptr[i] = v - c + add;
  if (threadIdx.x == 255) partials[blockIdx.x] = add + v;
}

__global__ __launch_bounds__(256) void scan_top(int* __restrict__ partials) {
  int t = threadIdx.x;
  int lane = t & 63, wv = t >> 6;
  int c = (t < SCAN_NB) ? partials[t] : 0;
  int v = c;
#pragma unroll
  for (int off = 1; off < 64; off <<= 1) {
    int u = __shfl_up(v, off);
    if (lane >= off) v += u;
  }
  __shared__ int wsum[4];
  if (lane == 63) wsum[wv] = v;
  __syncthreads();
  int add = 0;
  for (int w = 0; w < wv; ++w) add += wsum[w];
  if (t < SCAN_NB) partials[t] = v - c + add;
}

__global__ __launch_bounds__(256) void scan_fin(int* __restrict__ rowptr,
                                                const int* __restrict__ partials,
                                                int* __restrict__ fill) {
  int i = blockIdx.x * 256 + threadIdx.x;
  if (i >= N_NODES) return;
  int v = rowptr[i] + partials[blockIdx.x];
  rowptr[i] = v;
  fill[i] = v;
  if (i == 0) rowptr[N_NODES] = ET;
}

__global__ __launch_bounds__(256) void scatter_kernel(const int* __restrict__ src,
                                                      const int* __restrict__ dst,
                                                      int* __restrict__ fill,
                                                      int* __restrict__ csr_src) {
  int i = blockIdx.x * 256 + threadIdx.x;
  if (i >= ET) return;
  int s, d;
  if (i < N_EDGES) { s = src[i]; d = dst[i]; } else { s = d = i - N_EDGES; }
  int pos = atomicAdd(&fill[d], 1);
  csr_src[pos] = s;
}

// ---------------- W repack: all 3 layers -> B-fragment order, bf16 ----------------
__global__ __launch_bounds__(256) void repack_w(const float* __restrict__ W0,
                                                const float* __restrict__ W1,
                                                const float* __restrict__ W2,
                                                unsigned short* __restrict__ Wr) {
  int i = blockIdx.x * 256 + threadIdx.x;
  if (i >= 3 * 16384) return;
  int L = i >> 14, rem = i & 16383;
  int t  = rem >> 11;
  int ks = (rem >> 9) & 3;
  int ln = (rem >> 3) & 63;
  int j  = rem & 7;
  int k   = ks * 32 + (ln >> 4) * 8 + j;
  int col = t * 16 + (ln & 15);
  const float* W = (L == 0) ? W0 : ((L == 1) ? W1 : W2);
  Wr[i] = f2bf(W[k * 128 + col]);
}

// ---------------- MFMA gemm + BN/ReLU prologue + att-logit epilogue ----------------
__global__ __launch_bounds__(256) void gemm_mfma(const float* __restrict__ Xin,
                                                 const unsigned short* __restrict__ WrL,
                                                 const float* __restrict__ bna,
                                                 const float* __restrict__ g,
                                                 const float* __restrict__ be,
                                                 const float* __restrict__ a_src,
                                                 const float* __restrict__ a_dst,
                                                 unsigned short* __restrict__ Hbf,
                                                 float* __restrict__ als,
                                                 float* __restrict__ ald,
                                                 int doBN) {
  __shared__ unsigned short lds[4][16][128];
  int lane = threadIdx.x & 63;
  int wv   = threadIdx.x >> 6;
  int row0 = blockIdx.x * 64 + wv * 16;
  int gidx = lane & 15;
  int quad = lane >> 4;
  int rA   = row0 + gidx;
  int rAc  = rA < N_NODES ? rA : N_NODES - 1;
  int koff = quad * 8;

  f32x4 acc[8] = {};
#pragma unroll
  for (int ks = 0; ks < 4; ++ks) {
    int cb = ks * 32 + koff;
    const float4* xr = (const float4*)(Xin + (size_t)rAc * FDIM + cb);
    float4 xa = xr[0], xb = xr[1];
    float xv[8] = {xa.x, xa.y, xa.z, xa.w, xb.x, xb.y, xb.z, xb.w};
    bf16x8 afrag;
    if (doBN) {
#pragma unroll
      for (int j = 0; j < 8; ++j) {
        int c = cb + j;
        float mu  = bna[c] * (1.f / N_NODES);
        float var = bna[128 + c] * (1.f / N_NODES) - mu * mu;
        float v = (xv[j] - mu) * rsqrtf(var + BN_EPS) * g[c] + be[c];
        v = v > 0.f ? v : 0.f;
        afrag[j] = (short)f2bf(v);
      }
    } else {
#pragma unroll
      for (int j = 0; j < 8; ++j) afrag[j] = (short)f2bf(xv[j]);
    }
#pragma unroll
    for (int t = 0; t < 8; ++t) {
      bf16x8 bfrag = *(const bf16x8*)(WrL + ((size_t)((t * 4 + ks) * 64 + lane)) * 8);
      acc[t] = __builtin_amdgcn_mfma_f32_16x16x32_bf16(afrag, bfrag, acc[t], 0, 0, 0);
    }
  }

  // ---- attention-logit epilogue: lane holds D[row=(quad*4+r)][col=t*16+gidx]
  float vs[2][4] = {}, vd[2][4] = {};
#pragma unroll
  for (int t = 0; t < 8; ++t) {
    int col = t * 16 + gidx;
    float as = a_src[col], ad = a_dst[col];
    int hd = t >> 2;
#pragma unroll
    for (int r = 0; r < 4; ++r) {
      vs[hd][r] = fmaf(acc[t][r], as, vs[hd][r]);
      vd[hd][r] = fmaf(acc[t][r], ad, vd[hd][r]);
    }
  }
#pragma unroll
  for (int off = 1; off < 16; off <<= 1) {
#pragma unroll
    for (int hd = 0; hd < 2; ++hd)
#pragma unroll
      for (int r = 0; r < 4; ++r) {
        vs[hd][r] += __shfl_xor(vs[hd][r], off);
        vd[hd][r] += __shfl_xor(vd[hd][r], off);
      }
  }
  if (gidx == 0) {
#pragma unroll
    for (int r = 0; r < 4; ++r) {
      int row = row0 + quad * 4 + r;
      if (row < N_NODES) {
        als[row * 2 + 0] = vs[0][r]; als[row * 2 + 1] = vs[1][r];
        ald[row * 2 + 0] = vd[0][r]; ald[row * 2 + 1] = vd[1][r];
      }
    }
  }

  // ---- bf16 H store via LDS transpose ----
#pragma unroll
  for (int t = 0; t < 8; ++t)
#pragma unroll
    for (int r = 0; r < 4; ++r)
      lds[wv][quad * 4 + r][t * 16 + gidx] = f2bf(acc[t][r]);
  __syncthreads();
#pragma unroll
  for (int it = 0; it < 4; ++it) {
    int rloc = it * 4 + quad;
    int row = row0 + rloc;
    if (row < N_NODES)
      *(u16x8*)(Hbf + (size_t)row * FDIM + gidx * 8) = *(u16x8*)&lds[wv][rloc][gidx * 8];
  }
}

// ---------------- fused softmax-aggregate (no max shift) + BN stats ----------------
// One wave per node (grid exact: 50000 waves). Lane owns channels 2l,2l+1;
// lanes 0-31 = head 0, 32-63 = head 1 for the logit. Softmax without max
// subtraction (logits bounded; shift-invariant). 4-edge unroll with clamped
// 4-deep prefetch; csr/als loads are scalar (n via readfirstlane).
// mode 0: write A fp32 [N,128], accumulate BN sums into part[32][256].
// mode 2: head-mean + b2 -> out fp32 [N,64].
__global__ __launch_bounds__(256) void fused_agg(const int* __restrict__ rowptr,
                                                 const int* __restrict__ csr_src,
                                                 const unsigned* __restrict__ H2,
                                                 const float* __restrict__ als,
                                                 const float* __restrict__ ald,
                                                 float* __restrict__ A,
                                                 float* __restrict__ out,
                                                 const float* __restrict__ b2,
                                                 float* __restrict__ part,
                                                 int mode) {
  int lane = threadIdx.x & 63;
  bool hi = lane >= 32;
  int n = __builtin_amdgcn_readfirstlane((blockIdx.x * 256 + threadIdx.x) >> 6);
  int beg = rowptr[n], end = rowptr[n + 1];
  float2 adv = ((const float2*)ald)[n];
  float advh = hi ? adv.y : adv.x;

  // prime 4 consecutive regs starting at b0 (clamped so indices stay valid)
  int b0 = end - 4; if (b0 > beg) b0 = beg; if (b0 < 0) b0 = 0;
  int delta = beg - b0;
  int s0 = csr_src[b0], s1 = csr_src[b0 + 1], s2 = csr_src[b0 + 2], s3 = csr_src[b0 + 3];
  float2 A0 = ((const float2*)als)[s0];
  float2 A1 = ((const float2*)als)[s1];
  float2 A2 = ((const float2*)als)[s2];
  float2 A3 = ((const float2*)als)[s3];
  unsigned h0 = H2[(size_t)s0 * 64 + lane];
  unsigned h1 = H2[(size_t)s1 * 64 + lane];
  unsigned h2 = H2[(size_t)s2 * 64 + lane];
  unsigned h3 = H2[(size_t)s3 * 64 + lane];

  float l = 0.f, ox = 0.f, oy = 0.f;

#define STEP(AL, HH) { \
    float v_ = (hi ? AL.y : AL.x) + advh; \
    v_ = fmaxf(v_, SLOPE * v_); \
    float e_ = __expf(v_); \
    l += e_; \
    ox = fmaf(e_, bflo(HH), ox); \
    oy = fmaf(e_, bfhi(HH), oy); }

  int j = beg;
  for (; j + 4 <= end; j += 4) {
    int p = j + 4;
    int pp = p; if (pp > end - 4) pp = end - 4;   // end-4 >= beg here
    int t0 = csr_src[pp], t1 = csr_src[pp + 1], t2 = csr_src[pp + 2], t3 = csr_src[pp + 3];
    float2 B0 = ((const float2*)als)[t0];
    float2 B1 = ((const float2*)als)[t1];
    float2 B2 = ((const float2*)als)[t2];
    float2 B3 = ((const float2*)als)[t3];
    unsigned g0 = H2[(size_t)t0 * 64 + lane];
    unsigned g1 = H2[(size_t)t1 * 64 + lane];
    unsigned g2 = H2[(size_t)t2 * 64 + lane];
    unsigned g3 = H2[(size_t)t3 * 64 + lane];

    STEP(A0, h0); STEP(A1, h1); STEP(A2, h2); STEP(A3, h3);

    delta = p - pp;
    A0 = B0; A1 = B1; A2 = B2; A3 = B3;
    h0 = g0; h1 = g1; h2 = g2; h3 = g3;
  }
  // tail: regs hold edges (j - delta) + k; valid k in [delta, delta + rem)
  int rem = end - j;
  int hi_k = delta + rem;
  if (0 >= delta && 0 < hi_k) STEP(A0, h0);
  if (1 >= delta && 1 < hi_k) STEP(A1, h1);
  if (2 >= delta && 2 < hi_k) STEP(A2, h2);
  if (3 >= delta && 3 < hi_k) STEP(A3, h3);
#undef STEP

  float inv = 1.f / (l + 1e-16f);
  ox *= inv; oy *= inv;

  if (mode == 0) {
    float2 outv = {ox, oy};
    *(float2*)(A + (size_t)n * FDIM + lane * 2) = outv;
    // BN partial reduce across the block's 4 waves -> 32-slot spread atomics
    __shared__ float sh[4][4][64];
    int wv = threadIdx.x >> 6;
    sh[wv][0][lane] = ox;
    sh[wv][1][lane] = oy;
    sh[wv][2][lane] = ox * ox;
    sh[wv][3][lane] = oy * oy;
    __syncthreads();
    if (threadIdx.x < 64) {
      int t = threadIdx.x;
      float a0 = 0.f, a1 = 0.f, a2 = 0.f, a3 = 0.f;
#pragma unroll
      for (int w = 0; w < 4; ++w) {
        a0 += sh[w][0][t]; a1 += sh[w][1][t];
        a2 += sh[w][2][t]; a3 += sh[w][3][t];
      }
      float* slot = part + (blockIdx.x & 31) * 256;
      atomicAdd(&slot[2 * t],           a0);
      atomicAdd(&slot[2 * t + 1],       a1);
      atomicAdd(&slot[128 + 2 * t],     a2);
      atomicAdd(&slot[128 + 2 * t + 1], a3);
    }
  } else {
    float px = __shfl_xor(ox, 32);
    float py = __shfl_xor(oy, 32);
    if (lane < 32) {
      int c = lane * 2;
      float2 outv = {0.5f * (ox + px) + b2[c], 0.5f * (oy + py) + b2[c + 1]};
      *(float2*)(out + (size_t)n * 64 + c) = outv;
    }
  }
}

// sum the 32 BN partial slots -> bna[256]
__global__ __launch_bounds__(256) void reduce_bna(const float* __restrict__ part,
                                                  float* __restrict__ bna) {
  int c = threadIdx.x;
  float s = 0.f;
#pragma unroll
  for (int k = 0; k < 32; ++k) s += part[k * 256 + c];
  bna[c] = s;
}

extern "C" void kernel_launch(void* const* d_in, const int* in_sizes, int n_in,
                              void* d_out, int out_size, void* d_ws, size_t ws_size,
                              hipStream_t stream) {
  const float* x  = (const float*)d_in[0];
  const int*   ei = (const int*)d_in[1];
  const int* src = ei;
  const int* dst = ei + N_EDGES;

  const float* W[3]    = {(const float*)d_in[2],  (const float*)d_in[8],  (const float*)d_in[14]};
  const float* asrc[3] = {(const float*)d_in[3],  (const float*)d_in[9],  (const float*)d_in[15]};
  const float* adst[3] = {(const float*)d_in[4],  (const float*)d_in[10], (const float*)d_in[16]};
  const float* g[2]    = {(const float*)d_in[6],  (const float*)d_in[12]};
  const float* be[2]   = {(const float*)d_in[7],  (const float*)d_in[13]};
  const float* b2      = (const float*)d_in[17];

  // workspace (4-byte units, every region 16B-aligned):
  int*   counts   = (int*)d_ws;
  int*   rowptr   = counts + 50048;
  int*   fill     = rowptr + 50048;
  int*   partials = fill + 50048;
  int*   csr_src  = partials + 256;
  float* bna      = (float*)(csr_src + 850048);
  float* part     = bna + 256;                   // 32*256 BN partial slots
  float* als      = part + 8192;
  float* ald      = als + 100096;
  unsigned short* Wr  = (unsigned short*)(ald + 100096);
  unsigned short* Hbf = Wr + 3 * 16384;
  float* A        = (float*)(Hbf + (size_t)N_NODES * FDIM);

  // ---- build CSR + repack W (edge set / weights constant across layers) ----
  hipMemsetAsync(counts, 0, (size_t)N_NODES * sizeof(int), stream);
  hist_kernel<<<(ET + 255) / 256, 256, 0, stream>>>(dst, counts);
  scan_blk<<<SCAN_NB, 256, 0, stream>>>(counts, rowptr, partials);
  scan_top<<<1, 256, 0, stream>>>(partials);
  scan_fin<<<SCAN_NB, 256, 0, stream>>>(rowptr, partials, fill);
  scatter_kernel<<<(ET + 255) / 256, 256, 0, stream>>>(src, dst, fill, csr_src);
  repack_w<<<(3 * 16384 + 255) / 256, 256, 0, stream>>>(W[0], W[1], W[2], Wr);

  const int gemm_grid = (N_NODES + 63) / 64;
  const int agg_grid  = N_NODES * 64 / 256;   // 12500, exact (one wave/node)

  for (int L = 0; L < 3; ++L) {
    const float* fin = (L == 0) ? x : A;
    int doBN = (L > 0);
    const float* gg = doBN ? g[L - 1]  : (const float*)nullptr;
    const float* bb = doBN ? be[L - 1] : (const float*)nullptr;
    gemm_mfma<<<gemm_grid, 256, 0, stream>>>(fin, Wr + (size_t)L * 16384, bna, gg, bb,
                                             asrc[L], adst[L], Hbf, als, ald, doBN);
    if (L < 2)
      hipMemsetAsync(part, 0, 8192 * sizeof(float), stream);
    fused_agg<<<agg_grid, 256, 0, stream>>>(rowptr, csr_src, (const unsigned*)Hbf,
                                            als, ald, A, (float*)d_out, b2, part,
                                            (L == 2) ? 2 : 0);
    if (L < 2)
      reduce_bna<<<1, 256, 0, stream>>>(part, bna);
  }
}

// Round 8
// 360.686 us; speedup vs baseline: 1.4080x; 1.0323x over previous
//
#include <hip/hip_runtime.h>

// GAT 3-layer (N=50000, E=800000 (+N self loops), H=2, C=64, widths 128)
// Round 8: XCD-partitioned hist/scatter (dst-range = blockIdx&7; kills the
// 16x cross-XCD write amplification seen in R7: WRITE 54.5MB for a 3.4MB
// array), reduce_bna folded into gemm prologue (block-local sum of the 32
// BN partial slots -> LDS scale/shift).

#define N_NODES 50000
#define N_EDGES 800000
#define ET (N_EDGES + N_NODES)   // 850000 incl self loops
#define FDIM 128
#define SLOPE 0.2f
#define BN_EPS 1e-5f
#define SCAN_NB 196              // ceil(50000/256)
#define NRANGE 8
#define RNODES (N_NODES / NRANGE)        // 6250
#define SCAT_SUB 128
#define SCAT_CH ((ET + SCAT_SUB - 1) / SCAT_SUB)   // 6641

typedef __attribute__((ext_vector_type(8))) short bf16x8;
typedef __attribute__((ext_vector_type(4))) float f32x4;
typedef __attribute__((ext_vector_type(8))) unsigned short u16x8;

__device__ __forceinline__ unsigned short f2bf(float f) {
  unsigned u = __float_as_uint(f);
  u = u + 0x7fffu + ((u >> 16) & 1u);   // RNE
  return (unsigned short)(u >> 16);
}
__device__ __forceinline__ float bflo(unsigned p) { return __uint_as_float(p << 16); }
__device__ __forceinline__ float bfhi(unsigned p) { return __uint_as_float(p & 0xffff0000u); }

// ---------------- CSR build (XCD-partitioned by dst range) ----------------

__global__ __launch_bounds__(256) void hist_kernel(const int* __restrict__ dst,
                                                   int* __restrict__ counts) {
  int r = blockIdx.x & (NRANGE - 1);
  int s = blockIdx.x >> 3;
  int lo = r * RNODES, hi = lo + RNODES;
  int e0 = s * SCAT_CH;
  int e1 = e0 + SCAT_CH; if (e1 > ET) e1 = ET;
  for (int i = e0 + threadIdx.x; i < e1; i += 256) {
    int d = (i < N_EDGES) ? dst[i] : i - N_EDGES;
    if (d >= lo && d < hi) atomicAdd(&counts[d], 1);
  }
}

__global__ __launch_bounds__(256) void scan_blk(const int* __restrict__ counts,
                                                int* __restrict__ rowptr,
                                                int* __restrict__ partials) {
  int i = blockIdx.x * 256 + threadIdx.x;
  int lane = threadIdx.x & 63, wv = threadIdx.x >> 6;
  int c = (i < N_NODES) ? counts[i] : 0;
  int v = c;
#pragma unroll
  for (int off = 1; off < 64; off <<= 1) {
    int u = __shfl_up(v, off);
    if (lane >= off) v += u;
  }
  __shared__ int wsum[4];
  if (lane == 63) wsum[wv] = v;
  __syncthreads();
  int add = 0;
  for (int w = 0; w < wv; ++w) add += wsum[w];
  if (i < N_NODES) rowptr[i] = v - c + add;
  if (threadIdx.x == 255) partials[blockIdx.x] = add + v;
}

__global__ __launch_bounds__(256) void scan_top(int* __restrict__ partials) {
  int t = threadIdx.x;
  int lane = t & 63, wv = t >> 6;
  int c = (t < SCAN_NB) ? partials[t] : 0;
  int v = c;
#pragma unroll
  for (int off = 1; off < 64; off <<= 1) {
    int u = __shfl_up(v, off);
    if (lane >= off) v += u;
  }
  __shared__ int wsum[4];
  if (lane == 63) wsum[wv] = v;
  __syncthreads();
  int add = 0;
  for (int w = 0; w < wv; ++w) add += wsum[w];
  if (t < SCAN_NB) partials[t] = v - c + add;
}

__global__ __launch_bounds__(256) void scan_fin(int* __restrict__ rowptr,
                                                const int* __restrict__ partials,
                                                int* __restrict__ fill) {
  int i = blockIdx.x * 256 + threadIdx.x;
  if (i >= N_NODES) return;
  int v = rowptr[i] + partials[blockIdx.x];
  rowptr[i] = v;
  fill[i] = v;
  if (i == 0) rowptr[N_NODES] = ET;
}

__global__ __launch_bounds__(256) void scatter_kernel(const int* __restrict__ src,
                                                      const int* __restrict__ dst,
                                                      int* __restrict__ fill,
                                                      int* __restrict__ csr_src) {
  int r = blockIdx.x & (NRANGE - 1);
  int s = blockIdx.x >> 3;
  int lo = r * RNODES, hi = lo + RNODES;
  int e0 = s * SCAT_CH;
  int e1 = e0 + SCAT_CH; if (e1 > ET) e1 = ET;
  for (int i = e0 + threadIdx.x; i < e1; i += 256) {
    int d = (i < N_EDGES) ? dst[i] : i - N_EDGES;
    if (d >= lo && d < hi) {
      int sv = (i < N_EDGES) ? src[i] : d;
      int pos = atomicAdd(&fill[d], 1);
      csr_src[pos] = sv;
    }
  }
}

// ---------------- W repack: all 3 layers -> B-fragment order, bf16 ----------------
__global__ __launch_bounds__(256) void repack_w(const float* __restrict__ W0,
                                                const float* __restrict__ W1,
                                                const float* __restrict__ W2,
                                                unsigned short* __restrict__ Wr) {
  int i = blockIdx.x * 256 + threadIdx.x;
  if (i >= 3 * 16384) return;
  int L = i >> 14, rem = i & 16383;
  int t  = rem >> 11;
  int ks = (rem >> 9) & 3;
  int ln = (rem >> 3) & 63;
  int j  = rem & 7;
  int k   = ks * 32 + (ln >> 4) * 8 + j;
  int col = t * 16 + (ln & 15);
  const float* W = (L == 0) ? W0 : ((L == 1) ? W1 : W2);
  Wr[i] = f2bf(W[k * 128 + col]);
}

// ---------------- MFMA gemm + BN/ReLU prologue + att-logit epilogue ----------------
// doBN: prologue reduces the 32 BN partial slots (part[32][256]) to per-channel
// scale/shift in LDS, then x -> relu(x*scale+shift) before bf16 convert.
__global__ __launch_bounds__(256) void gemm_mfma(const float* __restrict__ Xin,
                                                 const unsigned short* __restrict__ WrL,
                                                 const float* __restrict__ part,
                                                 const float* __restrict__ g,
                                                 const float* __restrict__ be,
                                                 const float* __restrict__ a_src,
                                                 const float* __restrict__ a_dst,
                                                 unsigned short* __restrict__ Hbf,
                                                 float* __restrict__ als,
                                                 float* __restrict__ ald,
                                                 int doBN) {
  __shared__ unsigned short lds[4][16][128];
  __shared__ float ls_scale[128], ls_shift[128];
  int lane = threadIdx.x & 63;
  int wv   = threadIdx.x >> 6;

  if (doBN) {
    int t = threadIdx.x;
    if (t < 128) {
      float s = 0.f, q = 0.f;
#pragma unroll
      for (int k = 0; k < 32; ++k) {
        s += part[k * 256 + t];
        q += part[k * 256 + 128 + t];
      }
      float mu  = s * (1.f / N_NODES);
      float var = q * (1.f / N_NODES) - mu * mu;
      float sc  = rsqrtf(var + BN_EPS) * g[t];
      ls_scale[t] = sc;
      ls_shift[t] = be[t] - mu * sc;
    }
    __syncthreads();
  }

  int row0 = blockIdx.x * 64 + wv * 16;
  int gidx = lane & 15;
  int quad = lane >> 4;
  int rA   = row0 + gidx;
  int rAc  = rA < N_NODES ? rA : N_NODES - 1;
  int koff = quad * 8;

  f32x4 acc[8] = {};
#pragma unroll
  for (int ks = 0; ks < 4; ++ks) {
    int cb = ks * 32 + koff;
    const float4* xr = (const float4*)(Xin + (size_t)rAc * FDIM + cb);
    float4 xa = xr[0], xb = xr[1];
    float xv[8] = {xa.x, xa.y, xa.z, xa.w, xb.x, xb.y, xb.z, xb.w};
    bf16x8 afrag;
    if (doBN) {
#pragma unroll
      for (int j = 0; j < 8; ++j) {
        int c = cb + j;
        float v = fmaf(xv[j], ls_scale[c], ls_shift[c]);
        v = v > 0.f ? v : 0.f;
        afrag[j] = (short)f2bf(v);
      }
    } else {
#pragma unroll
      for (int j = 0; j < 8; ++j) afrag[j] = (short)f2bf(xv[j]);
    }
#pragma unroll
    for (int t = 0; t < 8; ++t) {
      bf16x8 bfrag = *(const bf16x8*)(WrL + ((size_t)((t * 4 + ks) * 64 + lane)) * 8);
      acc[t] = __builtin_amdgcn_mfma_f32_16x16x32_bf16(afrag, bfrag, acc[t], 0, 0, 0);
    }
  }

  // ---- attention-logit epilogue: lane holds D[row=(quad*4+r)][col=t*16+gidx]
  float vs[2][4] = {}, vd[2][4] = {};
#pragma unroll
  for (int t = 0; t < 8; ++t) {
    int col = t * 16 + gidx;
    float as = a_src[col], ad = a_dst[col];
    int hd = t >> 2;
#pragma unroll
    for (int r = 0; r < 4; ++r) {
      vs[hd][r] = fmaf(acc[t][r], as, vs[hd][r]);
      vd[hd][r] = fmaf(acc[t][r], ad, vd[hd][r]);
    }
  }
#pragma unroll
  for (int off = 1; off < 16; off <<= 1) {
#pragma unroll
    for (int hd = 0; hd < 2; ++hd)
#pragma unroll
      for (int r = 0; r < 4; ++r) {
        vs[hd][r] += __shfl_xor(vs[hd][r], off);
        vd[hd][r] += __shfl_xor(vd[hd][r], off);
      }
  }
  if (gidx == 0) {
#pragma unroll
    for (int r = 0; r < 4; ++r) {
      int row = row0 + quad * 4 + r;
      if (row < N_NODES) {
        als[row * 2 + 0] = vs[0][r]; als[row * 2 + 1] = vs[1][r];
        ald[row * 2 + 0] = vd[0][r]; ald[row * 2 + 1] = vd[1][r];
      }
    }
  }

  // ---- bf16 H store via LDS transpose ----
#pragma unroll
  for (int t = 0; t < 8; ++t)
#pragma unroll
    for (int r = 0; r < 4; ++r)
      lds[wv][quad * 4 + r][t * 16 + gidx] = f2bf(acc[t][r]);
  __syncthreads();
#pragma unroll
  for (int it = 0; it < 4; ++it) {
    int rloc = it * 4 + quad;
    int row = row0 + rloc;
    if (row < N_NODES)
      *(u16x8*)(Hbf + (size_t)row * FDIM + gidx * 8) = *(u16x8*)&lds[wv][rloc][gidx * 8];
  }
}

// ---------------- fused softmax-aggregate (no max shift) + BN stats ----------------
// One wave per node. Lane owns channels 2l,2l+1; lanes 0-31 = head 0,
// 32-63 = head 1 for the logit. 4-edge unroll with clamped 4-deep prefetch.
// mode 0: write A fp32 [N,128], accumulate BN sums into part[32][256].
// mode 2: head-mean + b2 -> out fp32 [N,64].
__global__ __launch_bounds__(256) void fused_agg(const int* __restrict__ rowptr,
                                                 const int* __restrict__ csr_src,
                                                 const unsigned* __restrict__ H2,
                                                 const float* __restrict__ als,
                                                 const float* __restrict__ ald,
                                                 float* __restrict__ A,
                                                 float* __restrict__ out,
                                                 const float* __restrict__ b2,
                                                 float* __restrict__ part,
                                                 int mode) {
  int lane = threadIdx.x & 63;
  bool hi = lane >= 32;
  int n = __builtin_amdgcn_readfirstlane((blockIdx.x * 256 + threadIdx.x) >> 6);
  int beg = rowptr[n], end = rowptr[n + 1];
  float2 adv = ((const float2*)ald)[n];
  float advh = hi ? adv.y : adv.x;

  int b0 = end - 4; if (b0 > beg) b0 = beg; if (b0 < 0) b0 = 0;
  int delta = beg - b0;
  int s0 = csr_src[b0], s1 = csr_src[b0 + 1], s2 = csr_src[b0 + 2], s3 = csr_src[b0 + 3];
  float2 A0 = ((const float2*)als)[s0];
  float2 A1 = ((const float2*)als)[s1];
  float2 A2 = ((const float2*)als)[s2];
  float2 A3 = ((const float2*)als)[s3];
  unsigned h0 = H2[(size_t)s0 * 64 + lane];
  unsigned h1 = H2[(size_t)s1 * 64 + lane];
  unsigned h2 = H2[(size_t)s2 * 64 + lane];
  unsigned h3 = H2[(size_t)s3 * 64 + lane];

  float l = 0.f, ox = 0.f, oy = 0.f;

#define STEP(AL, HH) { \
    float v_ = (hi ? AL.y : AL.x) + advh; \
    v_ = fmaxf(v_, SLOPE * v_); \
    float e_ = __expf(v_); \
    l += e_; \
    ox = fmaf(e_, bflo(HH), ox); \
    oy = fmaf(e_, bfhi(HH), oy); }

  int j = beg;
  for (; j + 4 <= end; j += 4) {
    int p = j + 4;
    int pp = p; if (pp > end - 4) pp = end - 4;   // end-4 >= beg here
    int t0 = csr_src[pp], t1 = csr_src[pp + 1], t2 = csr_src[pp + 2], t3 = csr_src[pp + 3];
    float2 B0 = ((const float2*)als)[t0];
    float2 B1 = ((const float2*)als)[t1];
    float2 B2 = ((const float2*)als)[t2];
    float2 B3 = ((const float2*)als)[t3];
    unsigned g0 = H2[(size_t)t0 * 64 + lane];
    unsigned g1 = H2[(size_t)t1 * 64 + lane];
    unsigned g2 = H2[(size_t)t2 * 64 + lane];
    unsigned g3 = H2[(size_t)t3 * 64 + lane];

    STEP(A0, h0); STEP(A1, h1); STEP(A2, h2); STEP(A3, h3);

    delta = p - pp;
    A0 = B0; A1 = B1; A2 = B2; A3 = B3;
    h0 = g0; h1 = g1; h2 = g2; h3 = g3;
  }
  int rem = end - j;
  int hi_k = delta + rem;
  if (0 >= delta && 0 < hi_k) STEP(A0, h0);
  if (1 >= delta && 1 < hi_k) STEP(A1, h1);
  if (2 >= delta && 2 < hi_k) STEP(A2, h2);
  if (3 >= delta && 3 < hi_k) STEP(A3, h3);
#undef STEP

  float inv = 1.f / (l + 1e-16f);
  ox *= inv; oy *= inv;

  if (mode == 0) {
    float2 outv = {ox, oy};
    *(float2*)(A + (size_t)n * FDIM + lane * 2) = outv;
    __shared__ float sh[4][4][64];
    int wv = threadIdx.x >> 6;
    sh[wv][0][lane] = ox;
    sh[wv][1][lane] = oy;
    sh[wv][2][lane] = ox * ox;
    sh[wv][3][lane] = oy * oy;
    __syncthreads();
    if (threadIdx.x < 64) {
      int t = threadIdx.x;
      float a0 = 0.f, a1 = 0.f, a2 = 0.f, a3 = 0.f;
#pragma unroll
      for (int w = 0; w < 4; ++w) {
        a0 += sh[w][0][t]; a1 += sh[w][1][t];
        a2 += sh[w][2][t]; a3 += sh[w][3][t];
      }
      float* slot = part + (blockIdx.x & 31) * 256;
      atomicAdd(&slot[2 * t],           a0);
      atomicAdd(&slot[2 * t + 1],       a1);
      atomicAdd(&slot[128 + 2 * t],     a2);
      atomicAdd(&slot[128 + 2 * t + 1], a3);
    }
  } else {
    float px = __shfl_xor(ox, 32);
    float py = __shfl_xor(oy, 32);
    if (lane < 32) {
      int c = lane * 2;
      float2 outv = {0.5f * (ox + px) + b2[c], 0.5f * (oy + py) + b2[c + 1]};
      *(float2*)(out + (size_t)n * 64 + c) = outv;
    }
  }
}

extern "C" void kernel_launch(void* const* d_in, const int* in_sizes, int n_in,
                              void* d_out, int out_size, void* d_ws, size_t ws_size,
                              hipStream_t stream) {
  const float* x  = (const float*)d_in[0];
  const int*   ei = (const int*)d_in[1];
  const int* src = ei;
  const int* dst = ei + N_EDGES;

  const float* W[3]    = {(const float*)d_in[2],  (const float*)d_in[8],  (const float*)d_in[14]};
  const float* asrc[3] = {(const float*)d_in[3],  (const float*)d_in[9],  (const float*)d_in[15]};
  const float* adst[3] = {(const float*)d_in[4],  (const float*)d_in[10], (const float*)d_in[16]};
  const float* g[2]    = {(const float*)d_in[6],  (const float*)d_in[12]};
  const float* be[2]   = {(const float*)d_in[7],  (const float*)d_in[13]};
  const float* b2      = (const float*)d_in[17];

  // workspace (4-byte units, every region 16B-aligned):
  int*   counts   = (int*)d_ws;
  int*   rowptr   = counts + 50048;
  int*   fill     = rowptr + 50048;
  int*   partials = fill + 50048;
  int*   csr_src  = partials + 256;
  float* part     = (float*)(csr_src + 850048);  // 32*256 BN partial slots
  float* als      = part + 8192;
  float* ald      = als + 100096;
  unsigned short* Wr  = (unsigned short*)(ald + 100096);
  unsigned short* Hbf = Wr + 3 * 16384;
  float* A        = (float*)(Hbf + (size_t)N_NODES * FDIM);

  // ---- build CSR + repack W (edge set / weights constant across layers) ----
  hipMemsetAsync(counts, 0, (size_t)N_NODES * sizeof(int), stream);
  hist_kernel<<<NRANGE * SCAT_SUB, 256, 0, stream>>>(dst, counts);
  scan_blk<<<SCAN_NB, 256, 0, stream>>>(counts, rowptr, partials);
  scan_top<<<1, 256, 0, stream>>>(partials);
  scan_fin<<<SCAN_NB, 256, 0, stream>>>(rowptr, partials, fill);
  scatter_kernel<<<NRANGE * SCAT_SUB, 256, 0, stream>>>(src, dst, fill, csr_src);
  repack_w<<<(3 * 16384 + 255) / 256, 256, 0, stream>>>(W[0], W[1], W[2], Wr);

  const int gemm_grid = (N_NODES + 63) / 64;
  const int agg_grid  = N_NODES * 64 / 256;   // 12500, exact (one wave/node)

  for (int L = 0; L < 3; ++L) {
    const float* fin = (L == 0) ? x : A;
    int doBN = (L > 0);
    const float* gg = doBN ? g[L - 1]  : (const float*)nullptr;
    const float* bb = doBN ? be[L - 1] : (const float*)nullptr;
    gemm_mfma<<<gemm_grid, 256, 0, stream>>>(fin, Wr + (size_t)L * 16384, part, gg, bb,
                                             asrc[L], adst[L], Hbf, als, ald, doBN);
    if (L < 2)
      hipMemsetAsync(part, 0, 8192 * sizeof(float), stream);  // after gemm consumed it
    fused_agg<<<agg_grid, 256, 0, stream>>>(rowptr, csr_src, (const unsigned*)Hbf,
                                            als, ald, A, (float*)d_out, b2, part,
                                            (L == 2) ? 2 : 0);
  }
}

// Round 9
// 345.109 us; speedup vs baseline: 1.4716x; 1.0451x over previous
//
#include <hip/hip_runtime.h>

// GAT 3-layer (N=50000, E=800000 (+N self loops), H=2, C=64, widths 128)
// Round 9: rank-based CSR build (hist_rank assigns per-edge rank via atomic,
// scatter_pos is atomic-free with fully coalesced reads — kills R8's 8x dst
// re-read + lane masking). A stored as bf16 (halves fused_agg write and
// gemm layer-1/2 fetch).

#define N_NODES 50000
#define N_EDGES 800000
#define ET (N_EDGES + N_NODES)   // 850000 incl self loops
#define FDIM 128
#define SLOPE 0.2f
#define BN_EPS 1e-5f
#define SCAN_NB 196              // ceil(50000/256)

typedef __attribute__((ext_vector_type(8))) short bf16x8;
typedef __attribute__((ext_vector_type(4))) float f32x4;
typedef __attribute__((ext_vector_type(8))) unsigned short u16x8;

__device__ __forceinline__ unsigned short f2bf(float f) {
  unsigned u = __float_as_uint(f);
  u = u + 0x7fffu + ((u >> 16) & 1u);   // RNE
  return (unsigned short)(u >> 16);
}
__device__ __forceinline__ float bflo(unsigned p) { return __uint_as_float(p << 16); }
__device__ __forceinline__ float bfhi(unsigned p) { return __uint_as_float(p & 0xffff0000u); }

// ---------------- CSR build (rank-based, atomic-free scatter) ----------------

__global__ __launch_bounds__(256) void hist_rank(const int* __restrict__ dst,
                                                 int* __restrict__ counts,
                                                 int* __restrict__ rank) {
  int i = blockIdx.x * 256 + threadIdx.x;
  if (i >= ET) return;
  int d = (i < N_EDGES) ? dst[i] : i - N_EDGES;
  rank[i] = atomicAdd(&counts[d], 1);
}

__global__ __launch_bounds__(256) void scan_blk(const int* __restrict__ counts,
                                                int* __restrict__ rowptr,
                                                int* __restrict__ partials) {
  int i = blockIdx.x * 256 + threadIdx.x;
  int lane = threadIdx.x & 63, wv = threadIdx.x >> 6;
  int c = (i < N_NODES) ? counts[i] : 0;
  int v = c;
#pragma unroll
  for (int off = 1; off < 64; off <<= 1) {
    int u = __shfl_up(v, off);
    if (lane >= off) v += u;
  }
  __shared__ int wsum[4];
  if (lane == 63) wsum[wv] = v;
  __syncthreads();
  int add = 0;
  for (int w = 0; w < wv; ++w) add += wsum[w];
  if (i < N_NODES) rowptr[i] = v - c + add;
  if (threadIdx.x == 255) partials[blockIdx.x] = add + v;
}

__global__ __launch_bounds__(256) void scan_top(int* __restrict__ partials) {
  int t = threadIdx.x;
  int lane = t & 63, wv = t >> 6;
  int c = (t < SCAN_NB) ? partials[t] : 0;
  int v = c;
#pragma unroll
  for (int off = 1; off < 64; off <<= 1) {
    int u = __shfl_up(v, off);
    if (lane >= off) v += u;
  }
  __shared__ int wsum[4];
  if (lane == 63) wsum[wv] = v;
  __syncthreads();
  int add = 0;
  for (int w = 0; w < wv; ++w) add += wsum[w];
  if (t < SCAN_NB) partials[t] = v - c + add;
}

__global__ __launch_bounds__(256) void scan_fin(int* __restrict__ rowptr,
                                                const int* __restrict__ partials) {
  int i = blockIdx.x * 256 + threadIdx.x;
  if (i >= N_NODES) return;
  rowptr[i] += partials[blockIdx.x];
  if (i == 0) rowptr[N_NODES] = ET;
}

__global__ __launch_bounds__(256) void scatter_pos(const int* __restrict__ src,
                                                   const int* __restrict__ dst,
                                                   const int* __restrict__ rowptr,
                                                   const int* __restrict__ rank,
                                                   int* __restrict__ csr_src) {
  int i = blockIdx.x * 256 + threadIdx.x;
  if (i >= ET) return;
  int d, s;
  if (i < N_EDGES) { d = dst[i]; s = src[i]; } else { d = s = i - N_EDGES; }
  csr_src[rowptr[d] + rank[i]] = s;
}

// ---------------- W repack: all 3 layers -> B-fragment order, bf16 ----------------
__global__ __launch_bounds__(256) void repack_w(const float* __restrict__ W0,
                                                const float* __restrict__ W1,
                                                const float* __restrict__ W2,
                                                unsigned short* __restrict__ Wr) {
  int i = blockIdx.x * 256 + threadIdx.x;
  if (i >= 3 * 16384) return;
  int L = i >> 14, rem = i & 16383;
  int t  = rem >> 11;
  int ks = (rem >> 9) & 3;
  int ln = (rem >> 3) & 63;
  int j  = rem & 7;
  int k   = ks * 32 + (ln >> 4) * 8 + j;
  int col = t * 16 + (ln & 15);
  const float* W = (L == 0) ? W0 : ((L == 1) ? W1 : W2);
  Wr[i] = f2bf(W[k * 128 + col]);
}

// ---------------- MFMA gemm + BN/ReLU prologue + att-logit epilogue ----------------
// inBF==0: Xin is fp32 [N,128], no BN (layer 0).
// inBF==1: Xin is bf16-packed u32 [N,64]; BN scale/shift from part[32][256]
//          applied + ReLU before the bf16 A-fragment convert.
__global__ __launch_bounds__(256) void gemm_mfma(const void* __restrict__ Xin,
                                                 const unsigned short* __restrict__ WrL,
                                                 const float* __restrict__ part,
                                                 const float* __restrict__ g,
                                                 const float* __restrict__ be,
                                                 const float* __restrict__ a_src,
                                                 const float* __restrict__ a_dst,
                                                 unsigned short* __restrict__ Hbf,
                                                 float* __restrict__ als,
                                                 float* __restrict__ ald,
                                                 int inBF) {
  __shared__ unsigned short lds[4][16][128];
  __shared__ float ls_scale[128], ls_shift[128];
  int lane = threadIdx.x & 63;
  int wv   = threadIdx.x >> 6;

  if (inBF) {
    int t = threadIdx.x;
    if (t < 128) {
      float s = 0.f, q = 0.f;
#pragma unroll
      for (int k = 0; k < 32; ++k) {
        s += part[k * 256 + t];
        q += part[k * 256 + 128 + t];
      }
      float mu  = s * (1.f / N_NODES);
      float var = q * (1.f / N_NODES) - mu * mu;
      float sc  = rsqrtf(var + BN_EPS) * g[t];
      ls_scale[t] = sc;
      ls_shift[t] = be[t] - mu * sc;
    }
    __syncthreads();
  }

  int row0 = blockIdx.x * 64 + wv * 16;
  int gidx = lane & 15;
  int quad = lane >> 4;
  int rA   = row0 + gidx;
  int rAc  = rA < N_NODES ? rA : N_NODES - 1;
  int koff = quad * 8;

  f32x4 acc[8] = {};
#pragma unroll
  for (int ks = 0; ks < 4; ++ks) {
    int cb = ks * 32 + koff;
    float xv[8];
    if (inBF) {
      const uint4* xr = (const uint4*)((const unsigned*)Xin + (size_t)rAc * 64 + (cb >> 1));
      uint4 xa = *xr;
      xv[0] = bflo(xa.x); xv[1] = bfhi(xa.x);
      xv[2] = bflo(xa.y); xv[3] = bfhi(xa.y);
      xv[4] = bflo(xa.z); xv[5] = bfhi(xa.z);
      xv[6] = bflo(xa.w); xv[7] = bfhi(xa.w);
    } else {
      const float4* xr = (const float4*)((const float*)Xin + (size_t)rAc * FDIM + cb);
      float4 xa = xr[0], xb = xr[1];
      xv[0] = xa.x; xv[1] = xa.y; xv[2] = xa.z; xv[3] = xa.w;
      xv[4] = xb.x; xv[5] = xb.y; xv[6] = xb.z; xv[7] = xb.w;
    }
    bf16x8 afrag;
    if (inBF) {
#pragma unroll
      for (int j = 0; j < 8; ++j) {
        int c = cb + j;
        float v = fmaf(xv[j], ls_scale[c], ls_shift[c]);
        v = v > 0.f ? v : 0.f;
        afrag[j] = (short)f2bf(v);
      }
    } else {
#pragma unroll
      for (int j = 0; j < 8; ++j) afrag[j] = (short)f2bf(xv[j]);
    }
#pragma unroll
    for (int t = 0; t < 8; ++t) {
      bf16x8 bfrag = *(const bf16x8*)(WrL + ((size_t)((t * 4 + ks) * 64 + lane)) * 8);
      acc[t] = __builtin_amdgcn_mfma_f32_16x16x32_bf16(afrag, bfrag, acc[t], 0, 0, 0);
    }
  }

  // ---- attention-logit epilogue: lane holds D[row=(quad*4+r)][col=t*16+gidx]
  float vs[2][4] = {}, vd[2][4] = {};
#pragma unroll
  for (int t = 0; t < 8; ++t) {
    int col = t * 16 + gidx;
    float as = a_src[col], ad = a_dst[col];
    int hd = t >> 2;
#pragma unroll
    for (int r = 0; r < 4; ++r) {
      vs[hd][r] = fmaf(acc[t][r], as, vs[hd][r]);
      vd[hd][r] = fmaf(acc[t][r], ad, vd[hd][r]);
    }
  }
#pragma unroll
  for (int off = 1; off < 16; off <<= 1) {
#pragma unroll
    for (int hd = 0; hd < 2; ++hd)
#pragma unroll
      for (int r = 0; r < 4; ++r) {
        vs[hd][r] += __shfl_xor(vs[hd][r], off);
        vd[hd][r] += __shfl_xor(vd[hd][r], off);
      }
  }
  if (gidx == 0) {
#pragma unroll
    for (int r = 0; r < 4; ++r) {
      int row = row0 + quad * 4 + r;
      if (row < N_NODES) {
        als[row * 2 + 0] = vs[0][r]; als[row * 2 + 1] = vs[1][r];
        ald[row * 2 + 0] = vd[0][r]; ald[row * 2 + 1] = vd[1][r];
      }
    }
  }

  // ---- bf16 H store via LDS transpose ----
#pragma unroll
  for (int t = 0; t < 8; ++t)
#pragma unroll
    for (int r = 0; r < 4; ++r)
      lds[wv][quad * 4 + r][t * 16 + gidx] = f2bf(acc[t][r]);
  __syncthreads();
#pragma unroll
  for (int it = 0; it < 4; ++it) {
    int rloc = it * 4 + quad;
    int row = row0 + rloc;
    if (row < N_NODES)
      *(u16x8*)(Hbf + (size_t)row * FDIM + gidx * 8) = *(u16x8*)&lds[wv][rloc][gidx * 8];
  }
}

// ---------------- fused softmax-aggregate (no max shift) + BN stats ----------------
// One wave per node. Lane owns channels 2l,2l+1; lanes 0-31 = head 0,
// 32-63 = head 1 for the logit. 4-edge unroll with clamped 4-deep prefetch.
// mode 0: write Abf (bf16 pair/u32) [N,64], accumulate BN sums into part[32][256].
// mode 2: head-mean + b2 -> out fp32 [N,64].
__global__ __launch_bounds__(256) void fused_agg(const int* __restrict__ rowptr,
                                                 const int* __restrict__ csr_src,
                                                 const unsigned* __restrict__ H2,
                                                 const float* __restrict__ als,
                                                 const float* __restrict__ ald,
                                                 unsigned* __restrict__ Abf,
                                                 float* __restrict__ out,
                                                 const float* __restrict__ b2,
                                                 float* __restrict__ part,
                                                 int mode) {
  int lane = threadIdx.x & 63;
  bool hi = lane >= 32;
  int n = __builtin_amdgcn_readfirstlane((blockIdx.x * 256 + threadIdx.x) >> 6);
  int beg = rowptr[n], end = rowptr[n + 1];
  float2 adv = ((const float2*)ald)[n];
  float advh = hi ? adv.y : adv.x;

  int b0 = end - 4; if (b0 > beg) b0 = beg; if (b0 < 0) b0 = 0;
  int delta = beg - b0;
  int s0 = csr_src[b0], s1 = csr_src[b0 + 1], s2 = csr_src[b0 + 2], s3 = csr_src[b0 + 3];
  float2 A0 = ((const float2*)als)[s0];
  float2 A1 = ((const float2*)als)[s1];
  float2 A2 = ((const float2*)als)[s2];
  float2 A3 = ((const float2*)als)[s3];
  unsigned h0 = H2[(size_t)s0 * 64 + lane];
  unsigned h1 = H2[(size_t)s1 * 64 + lane];
  unsigned h2 = H2[(size_t)s2 * 64 + lane];
  unsigned h3 = H2[(size_t)s3 * 64 + lane];

  float l = 0.f, ox = 0.f, oy = 0.f;

#define STEP(AL, HH) { \
    float v_ = (hi ? AL.y : AL.x) + advh; \
    v_ = fmaxf(v_, SLOPE * v_); \
    float e_ = __expf(v_); \
    l += e_; \
    ox = fmaf(e_, bflo(HH), ox); \
    oy = fmaf(e_, bfhi(HH), oy); }

  int j = beg;
  for (; j + 4 <= end; j += 4) {
    int p = j + 4;
    int pp = p; if (pp > end - 4) pp = end - 4;   // end-4 >= beg here
    int t0 = csr_src[pp], t1 = csr_src[pp + 1], t2 = csr_src[pp + 2], t3 = csr_src[pp + 3];
    float2 B0 = ((const float2*)als)[t0];
    float2 B1 = ((const float2*)als)[t1];
    float2 B2 = ((const float2*)als)[t2];
    float2 B3 = ((const float2*)als)[t3];
    unsigned g0 = H2[(size_t)t0 * 64 + lane];
    unsigned g1 = H2[(size_t)t1 * 64 + lane];
    unsigned g2 = H2[(size_t)t2 * 64 + lane];
    unsigned g3 = H2[(size_t)t3 * 64 + lane];

    STEP(A0, h0); STEP(A1, h1); STEP(A2, h2); STEP(A3, h3);

    delta = p - pp;
    A0 = B0; A1 = B1; A2 = B2; A3 = B3;
    h0 = g0; h1 = g1; h2 = g2; h3 = g3;
  }
  int rem = end - j;
  int hi_k = delta + rem;
  if (0 >= delta && 0 < hi_k) STEP(A0, h0);
  if (1 >= delta && 1 < hi_k) STEP(A1, h1);
  if (2 >= delta && 2 < hi_k) STEP(A2, h2);
  if (3 >= delta && 3 < hi_k) STEP(A3, h3);
#undef STEP

  float inv = 1.f / (l + 1e-16f);
  ox *= inv; oy *= inv;

  if (mode == 0) {
    unsigned pack = ((unsigned)f2bf(oy) << 16) | (unsigned)f2bf(ox);
    Abf[(size_t)n * 64 + lane] = pack;
    __shared__ float sh[4][4][64];
    int wv = threadIdx.x >> 6;
    sh[wv][0][lane] = ox;
    sh[wv][1][lane] = oy;
    sh[wv][2][lane] = ox * ox;
    sh[wv][3][lane] = oy * oy;
    __syncthreads();
    if (threadIdx.x < 64) {
      int t = threadIdx.x;
      float a0 = 0.f, a1 = 0.f, a2 = 0.f, a3 = 0.f;
#pragma unroll
      for (int w = 0; w < 4; ++w) {
        a0 += sh[w][0][t]; a1 += sh[w][1][t];
        a2 += sh[w][2][t]; a3 += sh[w][3][t];
      }
      float* slot = part + (blockIdx.x & 31) * 256;
      atomicAdd(&slot[2 * t],           a0);
      atomicAdd(&slot[2 * t + 1],       a1);
      atomicAdd(&slot[128 + 2 * t],     a2);
      atomicAdd(&slot[128 + 2 * t + 1], a3);
    }
  } else {
    float px = __shfl_xor(ox, 32);
    float py = __shfl_xor(oy, 32);
    if (lane < 32) {
      int c = lane * 2;
      float2 outv = {0.5f * (ox + px) + b2[c], 0.5f * (oy + py) + b2[c + 1]};
      *(float2*)(out + (size_t)n * 64 + c) = outv;
    }
  }
}

extern "C" void kernel_launch(void* const* d_in, const int* in_sizes, int n_in,
                              void* d_out, int out_size, void* d_ws, size_t ws_size,
                              hipStream_t stream) {
  const float* x  = (const float*)d_in[0];
  const int*   ei = (const int*)d_in[1];
  const int* src = ei;
  const int* dst = ei + N_EDGES;

  const float* W[3]    = {(const float*)d_in[2],  (const float*)d_in[8],  (const float*)d_in[14]};
  const float* asrc[3] = {(const float*)d_in[3],  (const float*)d_in[9],  (const float*)d_in[15]};
  const float* adst[3] = {(const float*)d_in[4],  (const float*)d_in[10], (const float*)d_in[16]};
  const float* g[2]    = {(const float*)d_in[6],  (const float*)d_in[12]};
  const float* be[2]   = {(const float*)d_in[7],  (const float*)d_in[13]};
  const float* b2      = (const float*)d_in[17];

  // workspace (4-byte units, every region 16B-aligned):
  int*   counts   = (int*)d_ws;
  int*   rowptr   = counts + 50048;
  int*   partials = rowptr + 50048;
  int*   rank     = partials + 256;
  int*   csr_src  = rank + 850048;
  float* part     = (float*)(csr_src + 850048);  // 32*256 BN partial slots
  float* als      = part + 8192;
  float* ald      = als + 100096;
  unsigned short* Wr  = (unsigned short*)(ald + 100096);
  unsigned short* Hbf = Wr + 3 * 16384;
  unsigned* Abf   = (unsigned*)(Hbf + (size_t)N_NODES * FDIM);   // bf16-pair [N,64]

  // ---- build CSR + repack W (edge set / weights constant across layers) ----
  hipMemsetAsync(counts, 0, (size_t)N_NODES * sizeof(int), stream);
  hist_rank<<<(ET + 255) / 256, 256, 0, stream>>>(dst, counts, rank);
  scan_blk<<<SCAN_NB, 256, 0, stream>>>(counts, rowptr, partials);
  scan_top<<<1, 256, 0, stream>>>(partials);
  scan_fin<<<SCAN_NB, 256, 0, stream>>>(rowptr, partials);
  scatter_pos<<<(ET + 255) / 256, 256, 0, stream>>>(src, dst, rowptr, rank, csr_src);
  repack_w<<<(3 * 16384 + 255) / 256, 256, 0, stream>>>(W[0], W[1], W[2], Wr);

  const int gemm_grid = (N_NODES + 63) / 64;
  const int agg_grid  = N_NODES * 64 / 256;   // 12500, exact (one wave/node)

  for (int L = 0; L < 3; ++L) {
    const void* fin = (L == 0) ? (const void*)x : (const void*)Abf;
    int inBF = (L > 0);
    const float* gg = inBF ? g[L - 1]  : (const float*)nullptr;
    const float* bb = inBF ? be[L - 1] : (const float*)nullptr;
    gemm_mfma<<<gemm_grid, 256, 0, stream>>>(fin, Wr + (size_t)L * 16384, part, gg, bb,
                                             asrc[L], adst[L], Hbf, als, ald, inBF);
    if (L < 2)
      hipMemsetAsync(part, 0, 8192 * sizeof(float), stream);  // after gemm consumed it
    fused_agg<<<agg_grid, 256, 0, stream>>>(rowptr, csr_src, (const unsigned*)Hbf,
                                            als, ald, Abf, (float*)d_out, b2, part,
                                            (L == 2) ? 2 : 0);
  }
}

// Round 10
// 339.796 us; speedup vs baseline: 1.4946x; 1.0156x over previous
//
#include <hip/hip_runtime.h>

// GAT 3-layer (N=50000, E=800000 (+N self loops), H=2, C=64, widths 128)
// Round 10: attention logits computed IN the gemm via 4 extra B columns
// (al = X @ (W·a), log2e baked in -> exp2f in fused_agg; kills the 128-op
// shfl epilogue); BN finalize as 1-block kernel (kills per-block 32-slot
// reduce prologue); fused_agg 8-deep prefetch; scan_top folded into scan_fin.

#define N_NODES 50000
#define N_EDGES 800000
#define ET (N_EDGES + N_NODES)   // 850000 incl self loops
#define FDIM 128
#define SLOPE 0.2f
#define BN_EPS 1e-5f
#define SCAN_NB 196              // ceil(50000/256)
#define LOG2E 1.44269504088896340736f
#define WSTRIDE 18432            // 9 tiles * 4 ks * 64 lanes * 8

typedef __attribute__((ext_vector_type(8))) short bf16x8;
typedef __attribute__((ext_vector_type(4))) float f32x4;
typedef __attribute__((ext_vector_type(8))) unsigned short u16x8;

__device__ __forceinline__ unsigned short f2bf(float f) {
  unsigned u = __float_as_uint(f);
  u = u + 0x7fffu + ((u >> 16) & 1u);   // RNE
  return (unsigned short)(u >> 16);
}
__device__ __forceinline__ float bflo(unsigned p) { return __uint_as_float(p << 16); }
__device__ __forceinline__ float bfhi(unsigned p) { return __uint_as_float(p & 0xffff0000u); }

// ---------------- CSR build (rank-based, atomic-free scatter) ----------------

__global__ __launch_bounds__(256) void hist_rank(const int* __restrict__ dst,
                                                 int* __restrict__ counts,
                                                 int* __restrict__ rank) {
  int i = blockIdx.x * 256 + threadIdx.x;
  if (i >= ET) return;
  int d = (i < N_EDGES) ? dst[i] : i - N_EDGES;
  rank[i] = atomicAdd(&counts[d], 1);
}

__global__ __launch_bounds__(256) void scan_blk(const int* __restrict__ counts,
                                                int* __restrict__ rowptr,
                                                int* __restrict__ partials) {
  int i = blockIdx.x * 256 + threadIdx.x;
  int lane = threadIdx.x & 63, wv = threadIdx.x >> 6;
  int c = (i < N_NODES) ? counts[i] : 0;
  int v = c;
#pragma unroll
  for (int off = 1; off < 64; off <<= 1) {
    int u = __shfl_up(v, off);
    if (lane >= off) v += u;
  }
  __shared__ int wsum[4];
  if (lane == 63) wsum[wv] = v;
  __syncthreads();
  int add = 0;
  for (int w = 0; w < wv; ++w) add += wsum[w];
  if (i < N_NODES) rowptr[i] = v - c + add;
  if (threadIdx.x == 255) partials[blockIdx.x] = add + v;
}

// final pass: each block reduces partials[0..blockIdx) inline (196 values)
__global__ __launch_bounds__(256) void scan_fin(int* __restrict__ rowptr,
                                                const int* __restrict__ partials) {
  __shared__ int sh[256];
  int t = threadIdx.x;
  sh[t] = (t < (int)blockIdx.x && t < SCAN_NB) ? partials[t] : 0;
  __syncthreads();
#pragma unroll
  for (int off = 128; off > 0; off >>= 1) {
    if (t < off) sh[t] += sh[t + off];
    __syncthreads();
  }
  int base = sh[0];
  int i = blockIdx.x * 256 + t;
  if (i < N_NODES) rowptr[i] += base;
  if (i == 0) rowptr[N_NODES] = ET;
}

__global__ __launch_bounds__(256) void scatter_pos(const int* __restrict__ src,
                                                   const int* __restrict__ dst,
                                                   const int* __restrict__ rowptr,
                                                   const int* __restrict__ rank,
                                                   int* __restrict__ csr_src) {
  int i = blockIdx.x * 256 + threadIdx.x;
  if (i >= ET) return;
  int d, s;
  if (i < N_EDGES) { d = dst[i]; s = src[i]; } else { d = s = i - N_EDGES; }
  csr_src[rowptr[d] + rank[i]] = s;
}

// ---------------- W repack: B-fragment order + 4 logit columns (tile 8) ----
// t<8: Wr[L][((t*4+ks)*64+ln)*8+j] = bf16(W[k][t*16+(ln&15)]), k=ks*32+(ln>>4)*8+j
// t==8, cl=(ln&15)<4: column = log2e * sum_c W[k][head*64+c]*a[head][c]
//   cl 0/1 = a_src head 0/1; cl 2/3 = a_dst head 0/1; cl>=4 zero.
__global__ __launch_bounds__(256) void repack_w(const float* __restrict__ W0,
                                                const float* __restrict__ W1,
                                                const float* __restrict__ W2,
                                                const float* __restrict__ as0,
                                                const float* __restrict__ as1,
                                                const float* __restrict__ as2,
                                                const float* __restrict__ ad0,
                                                const float* __restrict__ ad1,
                                                const float* __restrict__ ad2,
                                                unsigned short* __restrict__ Wr) {
  int i = blockIdx.x * 256 + threadIdx.x;
  if (i >= 3 * WSTRIDE) return;
  int L = i / WSTRIDE, rem = i % WSTRIDE;
  int t  = rem >> 11;
  int ks = (rem >> 9) & 3;
  int ln = (rem >> 3) & 63;
  int j  = rem & 7;
  int k  = ks * 32 + (ln >> 4) * 8 + j;
  const float* W = (L == 0) ? W0 : ((L == 1) ? W1 : W2);
  float val;
  if (t < 8) {
    int col = t * 16 + (ln & 15);
    val = W[k * 128 + col];
  } else {
    int cl = ln & 15;
    if (cl < 4) {
      int head = cl & 1;
      const float* a = (cl < 2) ? ((L == 0) ? as0 : (L == 1) ? as1 : as2)
                                : ((L == 0) ? ad0 : (L == 1) ? ad1 : ad2);
      float s = 0.f;
      const float* wrow = W + k * 128 + head * 64;
      const float* ah = a + head * 64;
#pragma unroll 8
      for (int c = 0; c < 64; ++c) s = fmaf(wrow[c], ah[c], s);
      val = s * LOG2E;
    } else {
      val = 0.f;
    }
  }
  Wr[i] = f2bf(val);
}

// ---------------- BN finalize: part[32][256] -> lsbuf[256] (scale|shift) ----
__global__ __launch_bounds__(128) void bn_fin(const float* __restrict__ part,
                                              const float* __restrict__ g,
                                              const float* __restrict__ be,
                                              float* __restrict__ lsbuf) {
  int t = threadIdx.x;   // 0..127
  float s = 0.f, q = 0.f;
#pragma unroll
  for (int k = 0; k < 32; ++k) {
    s += part[k * 256 + t];
    q += part[k * 256 + 128 + t];
  }
  float mu  = s * (1.f / N_NODES);
  float var = q * (1.f / N_NODES) - mu * mu;
  float sc  = rsqrtf(var + BN_EPS) * g[t];
  lsbuf[t]       = sc;
  lsbuf[128 + t] = be[t] - mu * sc;
}

// ---------------- MFMA gemm (9 tiles: 8 H cols + logit cols) ----------------
// inBF==0: Xin fp32 [N,128], no BN (layer 0).
// inBF==1: Xin bf16-packed u32 [N,64]; BN scale/shift from lsbuf + ReLU.
// Outputs: Hbf bf16 [N,128] (LDS transpose), als/ald fp32 [N,2] (log2-scaled).
__global__ __launch_bounds__(256) void gemm_mfma(const void* __restrict__ Xin,
                                                 const unsigned short* __restrict__ WrL,
                                                 const float* __restrict__ lsbuf,
                                                 unsigned short* __restrict__ Hbf,
                                                 float* __restrict__ als,
                                                 float* __restrict__ ald,
                                                 int inBF) {
  __shared__ unsigned short lds[4][16][128];
  __shared__ float ls_scale[128], ls_shift[128];
  int lane = threadIdx.x & 63;
  int wv   = threadIdx.x >> 6;

  if (inBF) {
    int t = threadIdx.x;
    if (t < 128) {
      ls_scale[t] = lsbuf[t];
      ls_shift[t] = lsbuf[128 + t];
    }
    __syncthreads();
  }

  int row0 = blockIdx.x * 64 + wv * 16;
  int gidx = lane & 15;
  int quad = lane >> 4;
  int rA   = row0 + gidx;
  int rAc  = rA < N_NODES ? rA : N_NODES - 1;
  int koff = quad * 8;

  f32x4 acc[9] = {};
#pragma unroll
  for (int ks = 0; ks < 4; ++ks) {
    int cb = ks * 32 + koff;
    float xv[8];
    if (inBF) {
      const uint4* xr = (const uint4*)((const unsigned*)Xin + (size_t)rAc * 64 + (cb >> 1));
      uint4 xa = *xr;
      xv[0] = bflo(xa.x); xv[1] = bfhi(xa.x);
      xv[2] = bflo(xa.y); xv[3] = bfhi(xa.y);
      xv[4] = bflo(xa.z); xv[5] = bfhi(xa.z);
      xv[6] = bflo(xa.w); xv[7] = bfhi(xa.w);
    } else {
      const float4* xr = (const float4*)((const float*)Xin + (size_t)rAc * FDIM + cb);
      float4 xa = xr[0], xb = xr[1];
      xv[0] = xa.x; xv[1] = xa.y; xv[2] = xa.z; xv[3] = xa.w;
      xv[4] = xb.x; xv[5] = xb.y; xv[6] = xb.z; xv[7] = xb.w;
    }
    bf16x8 afrag;
    if (inBF) {
#pragma unroll
      for (int j = 0; j < 8; ++j) {
        int c = cb + j;
        float v = fmaf(xv[j], ls_scale[c], ls_shift[c]);
        v = v > 0.f ? v : 0.f;
        afrag[j] = (short)f2bf(v);
      }
    } else {
#pragma unroll
      for (int j = 0; j < 8; ++j) afrag[j] = (short)f2bf(xv[j]);
    }
#pragma unroll
    for (int t = 0; t < 9; ++t) {
      bf16x8 bfrag = *(const bf16x8*)(WrL + ((size_t)((t * 4 + ks) * 64 + lane)) * 8);
      acc[t] = __builtin_amdgcn_mfma_f32_16x16x32_bf16(afrag, bfrag, acc[t], 0, 0, 0);
    }
  }

  // ---- logit columns: lane (quad,gidx<4) holds al[row=quad*4+r][gidx] ----
  if (gidx < 4) {
    float* dp = (gidx < 2) ? als : ald;
    int hd = gidx & 1;
#pragma unroll
    for (int r = 0; r < 4; ++r) {
      int row = row0 + quad * 4 + r;
      if (row < N_NODES) dp[row * 2 + hd] = acc[8][r];
    }
  }

  // ---- bf16 H store via LDS transpose ----
#pragma unroll
  for (int t = 0; t < 8; ++t)
#pragma unroll
    for (int r = 0; r < 4; ++r)
      lds[wv][quad * 4 + r][t * 16 + gidx] = f2bf(acc[t][r]);
  __syncthreads();
#pragma unroll
  for (int it = 0; it < 4; ++it) {
    int rloc = it * 4 + quad;
    int row = row0 + rloc;
    if (row < N_NODES)
      *(u16x8*)(Hbf + (size_t)row * FDIM + gidx * 8) = *(u16x8*)&lds[wv][rloc][gidx * 8];
  }
}

// ---------------- fused softmax-aggregate (exp2, 8-deep prefetch) ----------
// One wave per node. Lane owns channels 2l,2l+1; lanes 0-31 = head 0,
// 32-63 = head 1. Logits are log2-scaled -> exp2f. No max shift.
// mode 0: write Abf (bf16 pair/u32) [N,64] + BN sums into part[32][256].
// mode 2: head-mean + b2 -> out fp32 [N,64].
__global__ __launch_bounds__(256) void fused_agg(const int* __restrict__ rowptr,
                                                 const int* __restrict__ csr_src,
                                                 const unsigned* __restrict__ H2,
                                                 const float* __restrict__ als,
                                                 const float* __restrict__ ald,
                                                 unsigned* __restrict__ Abf,
                                                 float* __restrict__ out,
                                                 const float* __restrict__ b2,
                                                 float* __restrict__ part,
                                                 int mode) {
  int lane = threadIdx.x & 63;
  bool hi = lane >= 32;
  int n = __builtin_amdgcn_readfirstlane((blockIdx.x * 256 + threadIdx.x) >> 6);
  int beg = rowptr[n], end = rowptr[n + 1];
  float2 adv = ((const float2*)ald)[n];
  float advh = hi ? adv.y : adv.x;

  int b0 = end - 8; if (b0 > beg) b0 = beg; if (b0 < 0) b0 = 0;
  int delta = beg - b0;
  int sa[8]; float2 aa[8]; unsigned ha[8];
#pragma unroll
  for (int i = 0; i < 8; ++i) sa[i] = csr_src[b0 + i];
#pragma unroll
  for (int i = 0; i < 8; ++i) {
    aa[i] = ((const float2*)als)[sa[i]];
    ha[i] = H2[(size_t)sa[i] * 64 + lane];
  }

  float l = 0.f, ox = 0.f, oy = 0.f;

#define STEP(i) { \
    float v_ = (hi ? aa[i].y : aa[i].x) + advh; \
    v_ = fmaxf(v_, SLOPE * v_); \
    float e_ = exp2f(v_); \
    l += e_; \
    ox = fmaf(e_, bflo(ha[i]), ox); \
    oy = fmaf(e_, bfhi(ha[i]), oy); }

  int j = beg;
  for (; j + 8 <= end; j += 8) {
    int pp = j + 8; if (pp > end - 8) pp = end - 8;   // end-8 >= beg here
    int sn[8]; float2 an[8]; unsigned hn[8];
#pragma unroll
    for (int i = 0; i < 8; ++i) sn[i] = csr_src[pp + i];
#pragma unroll
    for (int i = 0; i < 8; ++i) {
      an[i] = ((const float2*)als)[sn[i]];
      hn[i] = H2[(size_t)sn[i] * 64 + lane];
    }
    STEP(0); STEP(1); STEP(2); STEP(3); STEP(4); STEP(5); STEP(6); STEP(7);
    delta = j + 8 - pp;
#pragma unroll
    for (int i = 0; i < 8; ++i) { aa[i] = an[i]; ha[i] = hn[i]; }
  }
  int rem = end - j;
  int hik = delta + rem;
  if (0 >= delta && 0 < hik) STEP(0);
  if (1 >= delta && 1 < hik) STEP(1);
  if (2 >= delta && 2 < hik) STEP(2);
  if (3 >= delta && 3 < hik) STEP(3);
  if (4 >= delta && 4 < hik) STEP(4);
  if (5 >= delta && 5 < hik) STEP(5);
  if (6 >= delta && 6 < hik) STEP(6);
  if (7 >= delta && 7 < hik) STEP(7);
#undef STEP

  float inv = 1.f / (l + 1e-16f);
  ox *= inv; oy *= inv;

  if (mode == 0) {
    unsigned pack = ((unsigned)f2bf(oy) << 16) | (unsigned)f2bf(ox);
    Abf[(size_t)n * 64 + lane] = pack;
    __shared__ float sh[4][4][64];
    int wv = threadIdx.x >> 6;
    sh[wv][0][lane] = ox;
    sh[wv][1][lane] = oy;
    sh[wv][2][lane] = ox * ox;
    sh[wv][3][lane] = oy * oy;
    __syncthreads();
    if (threadIdx.x < 64) {
      int t = threadIdx.x;
      float a0 = 0.f, a1 = 0.f, a2 = 0.f, a3 = 0.f;
#pragma unroll
      for (int w = 0; w < 4; ++w) {
        a0 += sh[w][0][t]; a1 += sh[w][1][t];
        a2 += sh[w][2][t]; a3 += sh[w][3][t];
      }
      float* slot = part + (blockIdx.x & 31) * 256;
      atomicAdd(&slot[2 * t],           a0);
      atomicAdd(&slot[2 * t + 1],       a1);
      atomicAdd(&slot[128 + 2 * t],     a2);
      atomicAdd(&slot[128 + 2 * t + 1], a3);
    }
  } else {
    float px = __shfl_xor(ox, 32);
    float py = __shfl_xor(oy, 32);
    if (lane < 32) {
      int c = lane * 2;
      float2 outv = {0.5f * (ox + px) + b2[c], 0.5f * (oy + py) + b2[c + 1]};
      *(float2*)(out + (size_t)n * 64 + c) = outv;
    }
  }
}

extern "C" void kernel_launch(void* const* d_in, const int* in_sizes, int n_in,
                              void* d_out, int out_size, void* d_ws, size_t ws_size,
                              hipStream_t stream) {
  const float* x  = (const float*)d_in[0];
  const int*   ei = (const int*)d_in[1];
  const int* src = ei;
  const int* dst = ei + N_EDGES;

  const float* W[3]    = {(const float*)d_in[2],  (const float*)d_in[8],  (const float*)d_in[14]};
  const float* asrc[3] = {(const float*)d_in[3],  (const float*)d_in[9],  (const float*)d_in[15]};
  const float* adst[3] = {(const float*)d_in[4],  (const float*)d_in[10], (const float*)d_in[16]};
  const float* g[2]    = {(const float*)d_in[6],  (const float*)d_in[12]};
  const float* be[2]   = {(const float*)d_in[7],  (const float*)d_in[13]};
  const float* b2      = (const float*)d_in[17];

  // workspace (4-byte units, regions 16B-aligned):
  int*   counts   = (int*)d_ws;
  int*   rowptr   = counts + 50048;
  int*   partials = rowptr + 50048;
  int*   rank     = partials + 256;
  int*   csr_src  = rank + 850048;
  float* part     = (float*)(csr_src + 850048);  // 32*256 BN partial slots
  float* lsbuf    = part + 8192;                  // 256 scale|shift
  float* als      = lsbuf + 256;
  float* ald      = als + 100096;
  unsigned short* Wr  = (unsigned short*)(ald + 100096);   // 3*WSTRIDE u16
  unsigned short* Hbf = Wr + 3 * WSTRIDE + 128;            // pad to 16B align
  unsigned* Abf   = (unsigned*)(Hbf + (size_t)N_NODES * FDIM);

  // ---- build CSR + repack W (edge set / weights constant across layers) ----
  hipMemsetAsync(counts, 0, (size_t)N_NODES * sizeof(int), stream);
  hist_rank<<<(ET + 255) / 256, 256, 0, stream>>>(dst, counts, rank);
  scan_blk<<<SCAN_NB, 256, 0, stream>>>(counts, rowptr, partials);
  scan_fin<<<SCAN_NB, 256, 0, stream>>>(rowptr, partials);
  scatter_pos<<<(ET + 255) / 256, 256, 0, stream>>>(src, dst, rowptr, rank, csr_src);
  repack_w<<<(3 * WSTRIDE + 255) / 256, 256, 0, stream>>>(
      W[0], W[1], W[2], asrc[0], asrc[1], asrc[2], adst[0], adst[1], adst[2], Wr);

  const int gemm_grid = (N_NODES + 63) / 64;
  const int agg_grid  = N_NODES * 64 / 256;   // 12500, exact (one wave/node)

  for (int L = 0; L < 3; ++L) {
    const void* fin = (L == 0) ? (const void*)x : (const void*)Abf;
    int inBF = (L > 0);
    gemm_mfma<<<gemm_grid, 256, 0, stream>>>(fin, Wr + (size_t)L * WSTRIDE, lsbuf,
                                             Hbf, als, ald, inBF);
    if (L < 2)
      hipMemsetAsync(part, 0, 8192 * sizeof(float), stream);
    fused_agg<<<agg_grid, 256, 0, stream>>>(rowptr, csr_src, (const unsigned*)Hbf,
                                            als, ald, Abf, (float*)d_out, b2, part,
                                            (L == 2) ? 2 : 0);
    if (L < 2)
      bn_fin<<<1, 128, 0, stream>>>(part, g[L], be[L], lsbuf);
  }
}